// Round 10
// baseline (141.817 us; speedup 1.0000x reference)
//
#include <hip/hip_runtime.h>
#include <math.h>

#define NN 256
#define FEAT 1024
#define HIDR 256
#define GCNH 256
#define M1 1024            // HEADS*GCNH
#define OUTC 21
#define MAXDEG (NN + 1)    // up to 256 topk-incoming + 1 self loop
#define KC 16              // split-K factor
#define KCH (FEAT / KC)    // 64
#define RB 8               // rows per k_big block (16->8: 2x occupancy; r6
                           // showed k_big starved at low waves/CU, r9 showed
                           // per-wave prefetch depth alone doesn't fix it)
#define FCOLS 1536         // fused output cols: A(256) | B(256) | hpre(1024)

// ---------------------------------------------------------------------------
// 5-dispatch pipeline (round-8 structure, best 139.9 µs). This round: k_big
// occupancy 2x — grid 1536 (6 blocks/CU, 24 waves/CU). Latency tolerance
// scales with waves x prefetch-depth; depth-2 alone (r9) gained only 2 µs at
// 12 waves/CU, so the missing factor is waves.

// ---------------------------------------------------------------------------
// K1: split-K GEMM. LDS-staged feat, XCD-aware swizzle, P [row][kc][col],
// register prefetch depth 2. grid 1536 x 256: 32 rg x 3 cgy x 16 kc.
// Swizzle: id = xcd + 8*slot; g = xcd + 8*(slot>>5) (6 groups/XCD), rg =
// slot&31 — all 32 rg-blocks of a weight group land on one XCD's L2.
__global__ __launch_bounds__(256) void k_big(
        const float* __restrict__ feat, const float* __restrict__ Wfc1,
        const float* __restrict__ W1, float* __restrict__ P) {
    int id = blockIdx.x;
    int xcd = id & 7, slot = id >> 3;
    int g = xcd + 8 * (slot >> 5);       // weight group 0..47
    int rg = slot & 31;
    int cgy = g >> 4, kc = g & 15;       // g = cgy*16 + kc
    __shared__ float fS[RB][KCH];
    int tid = threadIdx.x;
    int r0 = rg * RB, k0 = kc * KCH;
    for (int x = tid; x < RB * KCH; x += 256) {
        int r = x >> 6, kk = x & (KCH - 1);
        fS[r][kk] = feat[(size_t)(r0 + r) * FEAT + k0 + kk];
    }
    __syncthreads();
    int gc = cgy * 512 + tid * 2;
    const float* pW;
    int ld;
    if (gc < 256)      { pW = Wfc1 + (size_t)k0 * HIDR + gc;                  ld = HIDR; }
    else if (gc < 512) { pW = Wfc1 + (size_t)(FEAT + k0) * HIDR + (gc - 256); ld = HIDR; }
    else               { pW = W1   + (size_t)k0 * M1 + (gc - 512);            ld = M1;   }
    float2 acc[RB];
#pragma unroll
    for (int r = 0; r < RB; r++) { acc[r].x = 0.f; acc[r].y = 0.f; }
    float2 w0 = *(const float2*)(pW);
    float2 w1 = *(const float2*)(pW + ld);
    float2 w2 = *(const float2*)(pW + 2 * ld);
    float2 w3 = *(const float2*)(pW + 3 * ld);
    float2 x0 = *(const float2*)(pW + 4 * ld);
    float2 x1 = *(const float2*)(pW + 5 * ld);
    float2 x2 = *(const float2*)(pW + 6 * ld);
    float2 x3 = *(const float2*)(pW + 7 * ld);
    for (int kk = 0; kk < KCH - 8; kk += 8) {
        pW += 8 * ld;
        float2 n0 = *(const float2*)(pW);
        float2 n1 = *(const float2*)(pW + ld);
        float2 n2 = *(const float2*)(pW + 2 * ld);
        float2 n3 = *(const float2*)(pW + 3 * ld);
        float2 m0 = *(const float2*)(pW + 4 * ld);
        float2 m1 = *(const float2*)(pW + 5 * ld);
        float2 m2 = *(const float2*)(pW + 6 * ld);
        float2 m3 = *(const float2*)(pW + 7 * ld);
#pragma unroll
        for (int r = 0; r < RB; r++) {
            float4 f = *(const float4*)&fS[r][kk];
            float4 h = *(const float4*)&fS[r][kk + 4];
            acc[r].x = fmaf(f.x, w0.x, acc[r].x); acc[r].y = fmaf(f.x, w0.y, acc[r].y);
            acc[r].x = fmaf(f.y, w1.x, acc[r].x); acc[r].y = fmaf(f.y, w1.y, acc[r].y);
            acc[r].x = fmaf(f.z, w2.x, acc[r].x); acc[r].y = fmaf(f.z, w2.y, acc[r].y);
            acc[r].x = fmaf(f.w, w3.x, acc[r].x); acc[r].y = fmaf(f.w, w3.y, acc[r].y);
            acc[r].x = fmaf(h.x, x0.x, acc[r].x); acc[r].y = fmaf(h.x, x0.y, acc[r].y);
            acc[r].x = fmaf(h.y, x1.x, acc[r].x); acc[r].y = fmaf(h.y, x1.y, acc[r].y);
            acc[r].x = fmaf(h.z, x2.x, acc[r].x); acc[r].y = fmaf(h.z, x2.y, acc[r].y);
            acc[r].x = fmaf(h.w, x3.x, acc[r].x); acc[r].y = fmaf(h.w, x3.y, acc[r].y);
        }
        w0 = n0; w1 = n1; w2 = n2; w3 = n3;
        x0 = m0; x1 = m1; x2 = m2; x3 = m3;
    }
    {   // epilogue: last 8 k-rows, no prefetch, no overshoot
        const int kk = KCH - 8;
#pragma unroll
        for (int r = 0; r < RB; r++) {
            float4 f = *(const float4*)&fS[r][kk];
            float4 h = *(const float4*)&fS[r][kk + 4];
            acc[r].x = fmaf(f.x, w0.x, acc[r].x); acc[r].y = fmaf(f.x, w0.y, acc[r].y);
            acc[r].x = fmaf(f.y, w1.x, acc[r].x); acc[r].y = fmaf(f.y, w1.y, acc[r].y);
            acc[r].x = fmaf(f.z, w2.x, acc[r].x); acc[r].y = fmaf(f.z, w2.y, acc[r].y);
            acc[r].x = fmaf(f.w, w3.x, acc[r].x); acc[r].y = fmaf(f.w, w3.y, acc[r].y);
            acc[r].x = fmaf(h.x, x0.x, acc[r].x); acc[r].y = fmaf(h.x, x0.y, acc[r].y);
            acc[r].x = fmaf(h.y, x1.x, acc[r].x); acc[r].y = fmaf(h.y, x1.y, acc[r].y);
            acc[r].x = fmaf(h.z, x2.x, acc[r].x); acc[r].y = fmaf(h.z, x2.y, acc[r].y);
            acc[r].x = fmaf(h.w, x3.x, acc[r].x); acc[r].y = fmaf(h.w, x3.y, acc[r].y);
        }
    }
    float* Pp = P + ((size_t)r0 * KC + kc) * FCOLS + gc;
#pragma unroll
    for (int r = 0; r < RB; r++)
        *(float2*)(Pp + (size_t)r * KC * FCOLS) = acc[r];
}

// ---------------------------------------------------------------------------
// Stage A: split-K reduce + route + geom fixup + es1/ed1 dots. grid 256 x 384.
__global__ __launch_bounds__(384) void k_stA(
        const float* __restrict__ P, const float* __restrict__ bfc1,
        const float* __restrict__ boxes, const int* __restrict__ imh,
        const int* __restrict__ imw, const float* __restrict__ W1,
        const float* __restrict__ as1, const float* __restrict__ ad1,
        float* __restrict__ A, float* __restrict__ BT4,
        float* __restrict__ hpre, float* __restrict__ es1,
        float* __restrict__ ed1) {
    __shared__ float gS[4];
    int row = blockIdx.x, tid = threadIdx.x;
    int c4 = tid * 4;
    const float* p = P + (size_t)row * (KC * FCOLS) + c4;
    float4 a0 = *(const float4*)(p);
    float4 a1 = *(const float4*)(p + FCOLS);
    float4 a2 = *(const float4*)(p + 2 * FCOLS);
    float4 a3 = *(const float4*)(p + 3 * FCOLS);
#pragma unroll
    for (int q = 4; q < KC; q += 4) {
        float4 t0 = *(const float4*)(p + (size_t)q * FCOLS);
        float4 t1 = *(const float4*)(p + (size_t)(q + 1) * FCOLS);
        float4 t2 = *(const float4*)(p + (size_t)(q + 2) * FCOLS);
        float4 t3 = *(const float4*)(p + (size_t)(q + 3) * FCOLS);
        a0.x += t0.x; a0.y += t0.y; a0.z += t0.z; a0.w += t0.w;
        a1.x += t1.x; a1.y += t1.y; a1.z += t1.z; a1.w += t1.w;
        a2.x += t2.x; a2.y += t2.y; a2.z += t2.z; a2.w += t2.w;
        a3.x += t3.x; a3.y += t3.y; a3.z += t3.z; a3.w += t3.w;
    }
    float4 s4;
    s4.x = (a0.x + a1.x) + (a2.x + a3.x);
    s4.y = (a0.y + a1.y) + (a2.y + a3.y);
    s4.z = (a0.z + a1.z) + (a2.z + a3.z);
    s4.w = (a0.w + a1.w) + (a2.w + a3.w);
    if (tid == 0) {
        float w = (float)imw[0], h = (float)imh[0];
        float x1 = boxes[row * 4 + 0] / w, y1 = boxes[row * 4 + 1] / h;
        float x2 = boxes[row * 4 + 2] / w, y2 = boxes[row * 4 + 3] / h;
        gS[0] = x1; gS[1] = y1; gS[2] = x2 - x1; gS[3] = y2 - y1;
    }
    __syncthreads();
    if (c4 < 256) {
        float4 bv = *(const float4*)(bfc1 + c4);
        s4.x += bv.x; s4.y += bv.y; s4.z += bv.z; s4.w += bv.w;
        *(float4*)(A + (size_t)row * HIDR + c4) = s4;
    } else if (c4 < 512) {
        int kk = c4 - 256;
        *(float4*)(BT4 + (size_t)(kk >> 2) * (NN * 4) + row * 4) = s4;
    } else {
        int ch = c4 - 512;
        float g0 = gS[0], g1 = gS[1], g2 = gS[2], g3 = gS[3];
        float4 wv;
        wv = *(const float4*)(W1 + (size_t)(FEAT + 0) * M1 + ch);
        s4.x = fmaf(g0, wv.x, s4.x); s4.y = fmaf(g0, wv.y, s4.y);
        s4.z = fmaf(g0, wv.z, s4.z); s4.w = fmaf(g0, wv.w, s4.w);
        wv = *(const float4*)(W1 + (size_t)(FEAT + 1) * M1 + ch);
        s4.x = fmaf(g1, wv.x, s4.x); s4.y = fmaf(g1, wv.y, s4.y);
        s4.z = fmaf(g1, wv.z, s4.z); s4.w = fmaf(g1, wv.w, s4.w);
        wv = *(const float4*)(W1 + (size_t)(FEAT + 2) * M1 + ch);
        s4.x = fmaf(g2, wv.x, s4.x); s4.y = fmaf(g2, wv.y, s4.y);
        s4.z = fmaf(g2, wv.z, s4.z); s4.w = fmaf(g2, wv.w, s4.w);
        wv = *(const float4*)(W1 + (size_t)(FEAT + 3) * M1 + ch);
        s4.x = fmaf(g3, wv.x, s4.x); s4.y = fmaf(g3, wv.y, s4.y);
        s4.z = fmaf(g3, wv.z, s4.z); s4.w = fmaf(g3, wv.w, s4.w);
        *(float4*)(hpre + (size_t)row * M1 + ch) = s4;
        float4 a = *(const float4*)(as1 + ch);
        float4 bv = *(const float4*)(ad1 + ch);
        float ps = s4.x * a.x + s4.y * a.y + s4.z * a.z + s4.w * a.w;
        float pd = s4.x * bv.x + s4.y * bv.y + s4.z * bv.z + s4.w * bv.w;
#pragma unroll
        for (int o = 32; o > 0; o >>= 1) {
            ps += __shfl_down(ps, o);
            pd += __shfl_down(pd, o);
        }
        if ((tid & 63) == 0) {
            int head = (tid - 128) >> 6;
            es1[row * 4 + head] = ps;
            ed1[row * 4 + head] = pd;
        }
    }
}

// ---------------------------------------------------------------------------
// Stage B: fused rel-row + top-3. grid 256 x 512.
__global__ __launch_bounds__(512) void k_stB(
        const float* __restrict__ A, const float* __restrict__ boxes,
        const float* __restrict__ Wfc1, const float* __restrict__ Wfc2,
        const float* __restrict__ BT4, int* __restrict__ idxTop) {
    __shared__ float As[HIDR];
    __shared__ float sval[512];
    __shared__ unsigned long long swk[8];
    __shared__ int win;
    int row = blockIdx.x, tid = threadIdx.x;
    if (tid < 256) As[tid] = A[(size_t)row * HIDR + tid];
    int j = tid & 255;
    float bi0 = boxes[row * 4 + 0], bi1 = boxes[row * 4 + 1];
    float bi2 = boxes[row * 4 + 2], bi3 = boxes[row * 4 + 3];
    float g0 = fabsf(bi0 - boxes[j * 4 + 0]);
    float g1 = fabsf(bi1 - boxes[j * 4 + 1]);
    float g2 = fabsf(bi2 - boxes[j * 4 + 2]);
    float g3 = fabsf(bi3 - boxes[j * 4 + 3]);
    __syncthreads();
    {
        int half = __builtin_amdgcn_readfirstlane(tid >> 8);  // wave-uniform
        int k0 = half * 128;
        const float* pB  = BT4 + (size_t)(k0 >> 2) * (NN * 4) + j * 4;
        const float* pA  = As + k0;                 // LDS broadcast
        const float* pW2 = Wfc2 + k0;
        const float* pg0 = Wfc1 + (size_t)(2 * FEAT + 0) * HIDR + k0;
        const float* pg1 = Wfc1 + (size_t)(2 * FEAT + 1) * HIDR + k0;
        const float* pg2 = Wfc1 + (size_t)(2 * FEAT + 2) * HIDR + k0;
        const float* pg3 = Wfc1 + (size_t)(2 * FEAT + 3) * HIDR + k0;
        float acc = 0.f;
#pragma unroll 4
        for (int kk = 0; kk < 128; kk += 4) {
            float4 a4 = *(const float4*)(pA + kk);
            float4 w4 = *(const float4*)(pW2 + kk);
            float4 q0 = *(const float4*)(pg0 + kk);
            float4 q1 = *(const float4*)(pg1 + kk);
            float4 q2 = *(const float4*)(pg2 + kk);
            float4 q3 = *(const float4*)(pg3 + kk);
            float4 b4 = *(const float4*)pB;
            pB += NN * 4;
            float v;
            v = a4.x + b4.x; v = fmaf(g0, q0.x, v); v = fmaf(g1, q1.x, v);
            v = fmaf(g2, q2.x, v); v = fmaf(g3, q3.x, v);
            acc = fmaf(fmaxf(v, 0.f), w4.x, acc);
            v = a4.y + b4.y; v = fmaf(g0, q0.y, v); v = fmaf(g1, q1.y, v);
            v = fmaf(g2, q2.y, v); v = fmaf(g3, q3.y, v);
            acc = fmaf(fmaxf(v, 0.f), w4.y, acc);
            v = a4.z + b4.z; v = fmaf(g0, q0.z, v); v = fmaf(g1, q1.z, v);
            v = fmaf(g2, q2.z, v); v = fmaf(g3, q3.z, v);
            acc = fmaf(fmaxf(v, 0.f), w4.z, acc);
            v = a4.w + b4.w; v = fmaf(g0, q0.w, v); v = fmaf(g1, q1.w, v);
            v = fmaf(g2, q2.w, v); v = fmaf(g3, q3.w, v);
            acc = fmaf(fmaxf(v, 0.f), w4.w, acc);
        }
        sval[tid] = acc;
    }
    __syncthreads();
    if (tid < 256) sval[tid] = sval[tid] + sval[tid + 256];
    __syncthreads();
    for (int r = 0; r < 4; r++) {
        unsigned long long key = 0ULL;
        if (tid < 256) {
            unsigned u = __float_as_uint(sval[tid]);
            u = (u & 0x80000000u) ? ~u : (u | 0x80000000u);
            key = ((unsigned long long)u << 32) | (unsigned)(NN - 1 - tid);
        }
#pragma unroll
        for (int o = 32; o > 0; o >>= 1) {
            unsigned long long nk = __shfl_down(key, o);
            if (nk > key) key = nk;
        }
        if ((tid & 63) == 0) swk[tid >> 6] = key;
        __syncthreads();
        if (tid == 0) {
            unsigned long long m = swk[0];
#pragma unroll
            for (int q = 1; q < 8; q++) if (swk[q] > m) m = swk[q];
            int wj = NN - 1 - (int)(m & 0xFFFFFFFFu);
            win = wj;
            if (r > 0) idxTop[row * 3 + (r - 1)] = wj;
        }
        __syncthreads();
        if (tid == win) sval[tid] = -1e38f;
        __syncthreads();
    }
}

// ---------------------------------------------------------------------------
// Stage C: ballot edge build + GAT-1 softmax/aggregate + h2 + es2/ed2.
// grid 256 x 512. Persists lst/deg to global for stage D.
__global__ __launch_bounds__(512) void k_stC(
        const int* __restrict__ idxTop, const float* __restrict__ es1,
        const float* __restrict__ ed1, const float* __restrict__ hpre,
        const float* __restrict__ b1, const float* __restrict__ W2,
        const float* __restrict__ as2, const float* __restrict__ ad2,
        int* __restrict__ deg, int* __restrict__ inlist,
        float* __restrict__ h2, float* __restrict__ es2,
        float* __restrict__ ed2) {
    __shared__ float sval[512];
    __shared__ int pfxw[4];
    __shared__ int lst[MAXDEG];
    __shared__ int dgS;
    __shared__ float sc[MAXDEG * 4];
    __shared__ float sh[M1];
    __shared__ float part[24 * OUTC];
    __shared__ float h2row[OUTC];
    int row = blockIdx.x, tid = threadIdx.x;
    int f = 0;
    if (tid < 256)
        f = (idxTop[tid * 3 + 0] == row) | (idxTop[tid * 3 + 1] == row)
          | (idxTop[tid * 3 + 2] == row);
    unsigned long long bm = __ballot(f);
    int lane = tid & 63, wv6 = tid >> 6;
    int rank = __popcll(bm & ((1ULL << lane) - 1ULL));
    if (tid < 256 && lane == 0) pfxw[wv6] = __popcll(bm);
    __syncthreads();
    {
        int base = 0;
#pragma unroll
        for (int w = 0; w < 4; w++) base += (w < wv6) ? pfxw[w] : 0;
        if (tid < 256 && f) {
            lst[base + rank] = tid;
            inlist[row * MAXDEG + base + rank] = tid;
        }
    }
    if (tid == 0) {
        int tot = pfxw[0] + pfxw[1] + pfxw[2] + pfxw[3];
        lst[tot] = row;                   // GATConv self loop
        inlist[row * MAXDEG + tot] = row;
        dgS = tot + 1;
        deg[row] = tot + 1;
    }
    __syncthreads();
    int dg = dgS;
    for (int p = tid; p < dg * 4; p += 512) {
        int e = p >> 2, hq2 = p & 3;
        int s = lst[e];
        float v = es1[s * 4 + hq2] + ed1[row * 4 + hq2];
        sc[p] = v >= 0.f ? v : 0.2f * v;  // leaky_relu(0.2)
    }
    __syncthreads();
    int hq = tid & 3;
    {
        float lm = -1e30f;
        for (int e = tid >> 2; e < dg; e += 128)
            lm = fmaxf(lm, sc[e * 4 + hq]);
#pragma unroll
        for (int o = 4; o <= 32; o <<= 1) lm = fmaxf(lm, __shfl_xor(lm, o));
        if (lane < 4) sval[wv6 * 4 + hq] = lm;
        __syncthreads();
        float m = sval[hq];
#pragma unroll
        for (int w = 1; w < 8; w++) m = fmaxf(m, sval[w * 4 + hq]);
        float ls = 0.f;
        for (int e = tid >> 2; e < dg; e += 128) {
            float pv = expf(sc[e * 4 + hq] - m);
            sc[e * 4 + hq] = pv;
            ls += pv;
        }
#pragma unroll
        for (int o = 4; o <= 32; o <<= 1) ls += __shfl_xor(ls, o);
        if (lane < 4) sval[32 + wv6 * 4 + hq] = ls;
        __syncthreads();
        float den = sval[32 + hq];
#pragma unroll
        for (int w = 1; w < 8; w++) den += sval[32 + w * 4 + hq];
        for (int e = tid >> 2; e < dg; e += 128)
            sc[e * 4 + hq] = sc[e * 4 + hq] / den;   // alpha
    }
    __syncthreads();
    {
        int col = tid & 255, hh = (tid >> 8) * 2;   // heads {hh, hh+1}
        float acc0 = 0.f, acc1 = 0.f;
        int e = 0;
        for (; e + 8 <= dg; e += 8) {
            float v0[8], v1[8];
#pragma unroll
            for (int u = 0; u < 8; u++) {
                const float* hs = hpre + (size_t)lst[e + u] * M1;
                v0[u] = hs[hh * GCNH + col];
                v1[u] = hs[(hh + 1) * GCNH + col];
            }
#pragma unroll
            for (int u = 0; u < 8; u++) {
                acc0 = fmaf(sc[(e + u) * 4 + hh],     v0[u], acc0);
                acc1 = fmaf(sc[(e + u) * 4 + hh + 1], v1[u], acc1);
            }
        }
        for (; e < dg; e++) {
            const float* hs = hpre + (size_t)lst[e] * M1;
            acc0 = fmaf(sc[e * 4 + hh],     hs[hh * GCNH + col],       acc0);
            acc1 = fmaf(sc[e * 4 + hh + 1], hs[(hh + 1) * GCNH + col], acc1);
        }
        int c0 = hh * GCNH + col, c1 = (hh + 1) * GCNH + col;
        sh[c0] = fmaxf(acc0 + b1[c0], 0.f);
        sh[c1] = fmaxf(acc1 + b1[c1], 0.f);
    }
    __syncthreads();
    if (tid < 504) {                      // 24-way split of 1024 -> 21
        int o = tid % OUTC, pq = tid / OUTC;
        float a2 = 0.f;
        for (int d = pq; d < M1; d += 24)
            a2 = fmaf(sh[d], W2[d * OUTC + o], a2);
        part[pq * OUTC + o] = a2;
    }
    __syncthreads();
    if (tid < OUTC) {
        float ssum = 0.f;
        for (int pq = 0; pq < 24; pq++) ssum += part[pq * OUTC + tid];
        h2[row * OUTC + tid] = ssum;
        h2row[tid] = ssum;
    }
    __syncthreads();
    if (tid == 0) {
        float ssum = 0.f, dd = 0.f;
        for (int k = 0; k < OUTC; k++) {
            ssum = fmaf(h2row[k], as2[k], ssum);
            dd = fmaf(h2row[k], ad2[k], dd);
        }
        es2[row] = ssum;
        ed2[row] = dd;
    }
}

// ---------------------------------------------------------------------------
// Stage D: GAT-2 softmax-aggregate -> logits + argmax. grid 256 x 512.
__global__ __launch_bounds__(512) void k_stD(
        const int* __restrict__ deg, const int* __restrict__ inlist,
        const float* __restrict__ es2, const float* __restrict__ ed2,
        const float* __restrict__ h2, const float* __restrict__ b2,
        float* __restrict__ out) {
    __shared__ float sval[512];
    __shared__ int lst[MAXDEG];
    __shared__ float scD[MAXDEG];
    __shared__ float part[24 * OUTC];
    __shared__ float lv[OUTC];
    int row = blockIdx.x, tid = threadIdx.x;
    int lane = tid & 63, wv6 = tid >> 6;
    int dgT = deg[row];
    float edt = ed2[row];
    for (int p = tid; p < dgT; p += 512) {
        int s = inlist[row * MAXDEG + p];
        lst[p] = s;
        float v = es2[s] + edt;
        scD[p] = v >= 0.f ? v : 0.2f * v;
    }
    __syncthreads();
    {
        float lm = -1e30f;
        for (int p = tid; p < dgT; p += 512) lm = fmaxf(lm, scD[p]);
#pragma unroll
        for (int o = 1; o <= 32; o <<= 1) lm = fmaxf(lm, __shfl_xor(lm, o));
        if (lane == 0) sval[wv6] = lm;
        __syncthreads();
        float m = sval[0];
#pragma unroll
        for (int w = 1; w < 8; w++) m = fmaxf(m, sval[w]);
        float ls = 0.f;
        for (int p = tid; p < dgT; p += 512) {
            float pv = expf(scD[p] - m);
            scD[p] = pv;
            ls += pv;
        }
#pragma unroll
        for (int o = 1; o <= 32; o <<= 1) ls += __shfl_xor(ls, o);
        if (lane == 0) sval[8 + wv6] = ls;
        __syncthreads();
        float den = sval[8];
#pragma unroll
        for (int w = 1; w < 8; w++) den += sval[8 + w];
        __syncthreads();
        if (tid < 504) {                  // (edge-group, out-channel) map
            int o = tid % OUTC, eg = tid / OUTC;
            float acc = 0.f;
            for (int e = eg; e < dgT; e += 24) {
                int s = lst[e];
                acc = fmaf(scD[e], h2[(size_t)s * OUTC + o], acc);
            }
            part[eg * OUTC + o] = acc;
        }
        __syncthreads();
        if (tid < OUTC) {
            float ssum = 0.f;
            for (int eg = 0; eg < 24; eg++) ssum += part[eg * OUTC + tid];
            float v = ssum / den + b2[tid];
            out[row * OUTC + tid] = v;
            lv[tid] = v;
        }
    }
    __syncthreads();
    if (tid == 0) {
        int best = 0;
        float bv = lv[0];
        for (int o = 1; o < OUTC; o++)
            if (lv[o] > bv) { bv = lv[o]; best = o; }  // first max wins
        out[NN * OUTC + row] = (float)best;
    }
}

// ---------------------------------------------------------------------------
extern "C" void kernel_launch(void* const* d_in, const int* in_sizes, int n_in,
                              void* d_out, int out_size, void* d_ws,
                              size_t ws_size, hipStream_t stream) {
    const float* feat  = (const float*)d_in[0];
    const float* boxes = (const float*)d_in[1];
    const float* Wfc1  = (const float*)d_in[2];
    const float* bfc1  = (const float*)d_in[3];
    const float* Wfc2  = (const float*)d_in[4];
    const float* bfc2  = (const float*)d_in[5];   (void)bfc2;
    const float* W1    = (const float*)d_in[6];
    const float* as1   = (const float*)d_in[7];
    const float* ad1   = (const float*)d_in[8];
    const float* b1    = (const float*)d_in[9];
    const float* W2    = (const float*)d_in[10];
    const float* as2   = (const float*)d_in[11];
    const float* ad2   = (const float*)d_in[12];
    const float* b2    = (const float*)d_in[13];
    const int*   imh   = (const int*)d_in[14];
    const int*   imw   = (const int*)d_in[15];

    float* ws = (float*)d_ws;
    float* P     = ws;  ws += KC * NN * FCOLS;   // 25 MB
    float* A     = ws;  ws += NN * HIDR;
    float* BT4   = ws;  ws += NN * HIDR;
    float* hpre  = ws;  ws += NN * M1;
    float* es1   = ws;  ws += NN * 4;
    float* ed1   = ws;  ws += NN * 4;
    float* h2    = ws;  ws += NN * OUTC;
    float* es2   = ws;  ws += NN;
    float* ed2   = ws;  ws += NN;
    int* idxTop  = (int*)ws;
    int* deg     = idxTop + NN * 3;
    int* inlist  = deg + NN;

    float* out = (float*)d_out;

    k_big<<<(NN / RB) * 3 * KC, 256, 0, stream>>>(feat, Wfc1, W1, P);
    k_stA<<<NN, 384, 0, stream>>>(P, bfc1, boxes, imh, imw, W1, as1, ad1,
                                  A, BT4, hpre, es1, ed1);
    k_stB<<<NN, 512, 0, stream>>>(A, boxes, Wfc1, Wfc2, BT4, idxTop);
    k_stC<<<NN, 512, 0, stream>>>(idxTop, es1, ed1, hpre, b1, W2, as2, ad2,
                                  deg, inlist, h2, es2, ed2);
    k_stD<<<NN, 512, 0, stream>>>(deg, inlist, es2, ed2, h2, b2, out);
}

// Round 11
// 140.477 us; speedup vs baseline: 1.0095x; 1.0095x over previous
//
#include <hip/hip_runtime.h>
#include <math.h>

#define NN 256
#define FEAT 1024
#define HIDR 256
#define GCNH 256
#define M1 1024            // HEADS*GCNH
#define OUTC 21
#define MAXDEG (NN + 1)    // up to 256 topk-incoming + 1 self loop
#define FCOLS 1536         // fused output cols: A(256) | B(256) | hpre(1024)
#define GBM 8              // k_gemm rows/block
#define GBN 64             // k_gemm cols/block
#define GKS 4              // k_gemm intra-block k-split (256 thr = 64c x 4kq)

// ---------------------------------------------------------------------------
// 4-dispatch pipeline. Rounds 8-10 showed: split-K k_big stuck at ~40 µs
// across KC/RB/prefetch knobs -> the cost is algorithmic (P 50 MB round-trip
// + weight re-streaming), not scheduling. This round: full-K-per-block GEMM
// producing FINAL outputs (A+bias, BT4 transposed, hpre+geom) -> P and
// stage A deleted; es1/ed1 dots folded into stB's prologue.

// ---------------------------------------------------------------------------
// K1: fused GEMM, full K per block. grid 768 (32 rg x 24 cg, XCD-swizzled:
// all 32 rg-blocks of a col-group on one XCD -> weight slab dedup in L2).
// 256 threads = 64 cols x 4 k-quarters; feat slab in LDS (broadcast reads);
// weights streamed coalesced (wave = 64 consecutive cols); 4 partials
// combined in LDS; epilogue applies region fixups and writes final buffers.
__global__ __launch_bounds__(256) void k_gemm(
        const float* __restrict__ feat, const float* __restrict__ Wfc1,
        const float* __restrict__ W1, const float* __restrict__ boxes,
        const int* __restrict__ imh, const int* __restrict__ imw,
        const float* __restrict__ bfc1, float* __restrict__ A,
        float* __restrict__ BT4, float* __restrict__ hpre) {
    __shared__ float fS[GBM][FEAT];       // 32 KB
    __shared__ float part[GKS][GBM][GBN]; // 8 KB
    __shared__ float gmS[GBM][4];
    int id = blockIdx.x;
    int xcd = id & 7, slot = id >> 3;
    int cg = xcd + 8 * (slot >> 5);       // col-group 0..23
    int rg = slot & 31;                   // row-group 0..31
    int r0 = rg * GBM, c0 = cg * GBN;
    int tid = threadIdx.x;
    for (int x = tid * 4; x < GBM * FEAT; x += 1024) {
        int r = x >> 10, k = x & (FEAT - 1);
        *(float4*)&fS[r][k] = *(const float4*)(feat + (size_t)(r0 + r) * FEAT + k);
    }
    __syncthreads();
    int c = tid & 63, kq = tid >> 6;      // kq wave-uniform
    int gc = c0 + c;
    const float* pW;
    int ldW;
    if (gc < 256)      { pW = Wfc1 + gc;                            ldW = HIDR; }
    else if (gc < 512) { pW = Wfc1 + (size_t)FEAT * HIDR + (gc - 256); ldW = HIDR; }
    else               { pW = W1 + (gc - 512);                      ldW = M1; }
    const float* pk = pW + (size_t)(kq * 256) * ldW;
    float acc[GBM];
#pragma unroll
    for (int r = 0; r < GBM; r++) acc[r] = 0.f;
    int kbeg = kq * 256;
    for (int k = kbeg; k < kbeg + 256; k += 8) {
        float w[8];
#pragma unroll
        for (int u = 0; u < 8; u++) w[u] = pk[(size_t)u * ldW];
        pk += 8 * (size_t)ldW;
#pragma unroll
        for (int r = 0; r < GBM; r++) {
            float4 f = *(const float4*)&fS[r][k];       // uniform -> broadcast
            float4 h = *(const float4*)&fS[r][k + 4];
            float a = acc[r];
            a = fmaf(f.x, w[0], a); a = fmaf(f.y, w[1], a);
            a = fmaf(f.z, w[2], a); a = fmaf(f.w, w[3], a);
            a = fmaf(h.x, w[4], a); a = fmaf(h.y, w[5], a);
            a = fmaf(h.z, w[6], a); a = fmaf(h.w, w[7], a);
            acc[r] = a;
        }
    }
#pragma unroll
    for (int r = 0; r < GBM; r++) part[kq][r][c] = acc[r];
    if (c0 >= 512 && tid < GBM) {         // geom factors for hpre fixup
        float w = (float)imw[0], h = (float)imh[0];
        float x1 = boxes[(r0 + tid) * 4 + 0] / w;
        float y1 = boxes[(r0 + tid) * 4 + 1] / h;
        float x2 = boxes[(r0 + tid) * 4 + 2] / w;
        float y2 = boxes[(r0 + tid) * 4 + 3] / h;
        gmS[tid][0] = x1; gmS[tid][1] = y1;
        gmS[tid][2] = x2 - x1; gmS[tid][3] = y2 - y1;
    }
    __syncthreads();
    for (int o = tid; o < GBM * GBN; o += 256) {   // 2 outputs/thread
        int r = o >> 6, cc = o & 63;
        float v = (part[0][r][cc] + part[1][r][cc])
                + (part[2][r][cc] + part[3][r][cc]);
        int gc2 = c0 + cc, grow = r0 + r;
        if (c0 < 256) {
            v += bfc1[gc2];
            A[(size_t)grow * HIDR + gc2] = v;
        } else if (c0 < 512) {
            int kk = gc2 - 256;
            BT4[(size_t)(kk >> 2) * (NN * 4) + grow * 4 + (kk & 3)] = v;
        } else {
            int ch = gc2 - 512;
            v = fmaf(gmS[r][0], W1[(size_t)(FEAT + 0) * M1 + ch], v);
            v = fmaf(gmS[r][1], W1[(size_t)(FEAT + 1) * M1 + ch], v);
            v = fmaf(gmS[r][2], W1[(size_t)(FEAT + 2) * M1 + ch], v);
            v = fmaf(gmS[r][3], W1[(size_t)(FEAT + 3) * M1 + ch], v);
            hpre[(size_t)grow * M1 + ch] = v;
        }
    }
}

// ---------------------------------------------------------------------------
// Stage B: es1/ed1 dots (prologue, folded from old stage A) + fused rel-row
// + top-3. grid 256 x 512.
__global__ __launch_bounds__(512) void k_stB(
        const float* __restrict__ A, const float* __restrict__ boxes,
        const float* __restrict__ Wfc1, const float* __restrict__ Wfc2,
        const float* __restrict__ BT4, const float* __restrict__ hpre,
        const float* __restrict__ as1, const float* __restrict__ ad1,
        int* __restrict__ idxTop, float* __restrict__ es1,
        float* __restrict__ ed1) {
    __shared__ float As[HIDR];
    __shared__ float sval[512];
    __shared__ unsigned long long swk[8];
    __shared__ float swE[8], swD[8];
    __shared__ int win;
    int row = blockIdx.x, tid = threadIdx.x;
    if (tid < 256) As[tid] = A[(size_t)row * HIDR + tid];
    {   // es1/ed1 for this row (consumed by stage C next dispatch)
        const float* hp = hpre + (size_t)row * M1;
        int ch = tid * 2;
        float2 hv = *(const float2*)(hp + ch);
        float2 av = *(const float2*)(as1 + ch);
        float2 dv = *(const float2*)(ad1 + ch);
        float ps = hv.x * av.x + hv.y * av.y;
        float pd = hv.x * dv.x + hv.y * dv.y;
#pragma unroll
        for (int o = 32; o > 0; o >>= 1) {
            ps += __shfl_down(ps, o);
            pd += __shfl_down(pd, o);
        }
        if ((tid & 63) == 0) { swE[tid >> 6] = ps; swD[tid >> 6] = pd; }
    }
    int j = tid & 255;
    float bi0 = boxes[row * 4 + 0], bi1 = boxes[row * 4 + 1];
    float bi2 = boxes[row * 4 + 2], bi3 = boxes[row * 4 + 3];
    float g0 = fabsf(bi0 - boxes[j * 4 + 0]);
    float g1 = fabsf(bi1 - boxes[j * 4 + 1]);
    float g2 = fabsf(bi2 - boxes[j * 4 + 2]);
    float g3 = fabsf(bi3 - boxes[j * 4 + 3]);
    __syncthreads();
    if (tid < 4) {   // heads map to wave pairs: head h = waves {2h, 2h+1}
        es1[row * 4 + tid] = swE[2 * tid] + swE[2 * tid + 1];
        ed1[row * 4 + tid] = swD[2 * tid] + swD[2 * tid + 1];
    }
    {
        int half = __builtin_amdgcn_readfirstlane(tid >> 8);  // wave-uniform
        int k0 = half * 128;
        const float* pB  = BT4 + (size_t)(k0 >> 2) * (NN * 4) + j * 4;
        const float* pA  = As + k0;                 // LDS broadcast
        const float* pW2 = Wfc2 + k0;
        const float* pg0 = Wfc1 + (size_t)(2 * FEAT + 0) * HIDR + k0;
        const float* pg1 = Wfc1 + (size_t)(2 * FEAT + 1) * HIDR + k0;
        const float* pg2 = Wfc1 + (size_t)(2 * FEAT + 2) * HIDR + k0;
        const float* pg3 = Wfc1 + (size_t)(2 * FEAT + 3) * HIDR + k0;
        float acc = 0.f;
#pragma unroll 4
        for (int kk = 0; kk < 128; kk += 4) {
            float4 a4 = *(const float4*)(pA + kk);
            float4 w4 = *(const float4*)(pW2 + kk);
            float4 q0 = *(const float4*)(pg0 + kk);
            float4 q1 = *(const float4*)(pg1 + kk);
            float4 q2 = *(const float4*)(pg2 + kk);
            float4 q3 = *(const float4*)(pg3 + kk);
            float4 b4 = *(const float4*)pB;
            pB += NN * 4;
            float v;
            v = a4.x + b4.x; v = fmaf(g0, q0.x, v); v = fmaf(g1, q1.x, v);
            v = fmaf(g2, q2.x, v); v = fmaf(g3, q3.x, v);
            acc = fmaf(fmaxf(v, 0.f), w4.x, acc);
            v = a4.y + b4.y; v = fmaf(g0, q0.y, v); v = fmaf(g1, q1.y, v);
            v = fmaf(g2, q2.y, v); v = fmaf(g3, q3.y, v);
            acc = fmaf(fmaxf(v, 0.f), w4.y, acc);
            v = a4.z + b4.z; v = fmaf(g0, q0.z, v); v = fmaf(g1, q1.z, v);
            v = fmaf(g2, q2.z, v); v = fmaf(g3, q3.z, v);
            acc = fmaf(fmaxf(v, 0.f), w4.z, acc);
            v = a4.w + b4.w; v = fmaf(g0, q0.w, v); v = fmaf(g1, q1.w, v);
            v = fmaf(g2, q2.w, v); v = fmaf(g3, q3.w, v);
            acc = fmaf(fmaxf(v, 0.f), w4.w, acc);
        }
        sval[tid] = acc;
    }
    __syncthreads();
    if (tid < 256) sval[tid] = sval[tid] + sval[tid + 256];
    __syncthreads();
    for (int r = 0; r < 4; r++) {
        unsigned long long key = 0ULL;
        if (tid < 256) {
            unsigned u = __float_as_uint(sval[tid]);
            u = (u & 0x80000000u) ? ~u : (u | 0x80000000u);
            key = ((unsigned long long)u << 32) | (unsigned)(NN - 1 - tid);
        }
#pragma unroll
        for (int o = 32; o > 0; o >>= 1) {
            unsigned long long nk = __shfl_down(key, o);
            if (nk > key) key = nk;
        }
        if ((tid & 63) == 0) swk[tid >> 6] = key;
        __syncthreads();
        if (tid == 0) {
            unsigned long long m = swk[0];
#pragma unroll
            for (int q = 1; q < 8; q++) if (swk[q] > m) m = swk[q];
            int wj = NN - 1 - (int)(m & 0xFFFFFFFFu);
            win = wj;
            if (r > 0) idxTop[row * 3 + (r - 1)] = wj;
        }
        __syncthreads();
        if (tid == win) sval[tid] = -1e38f;
        __syncthreads();
    }
}

// ---------------------------------------------------------------------------
// Stage C: ballot edge build + GAT-1 softmax/aggregate + h2 + es2/ed2.
// grid 256 x 512. Persists lst/deg to global for stage D.
__global__ __launch_bounds__(512) void k_stC(
        const int* __restrict__ idxTop, const float* __restrict__ es1,
        const float* __restrict__ ed1, const float* __restrict__ hpre,
        const float* __restrict__ b1, const float* __restrict__ W2,
        const float* __restrict__ as2, const float* __restrict__ ad2,
        int* __restrict__ deg, int* __restrict__ inlist,
        float* __restrict__ h2, float* __restrict__ es2,
        float* __restrict__ ed2) {
    __shared__ float sval[512];
    __shared__ int pfxw[4];
    __shared__ int lst[MAXDEG];
    __shared__ int dgS;
    __shared__ float sc[MAXDEG * 4];
    __shared__ float sh[M1];
    __shared__ float part[24 * OUTC];
    __shared__ float h2row[OUTC];
    int row = blockIdx.x, tid = threadIdx.x;
    int f = 0;
    if (tid < 256)
        f = (idxTop[tid * 3 + 0] == row) | (idxTop[tid * 3 + 1] == row)
          | (idxTop[tid * 3 + 2] == row);
    unsigned long long bm = __ballot(f);
    int lane = tid & 63, wv6 = tid >> 6;
    int rank = __popcll(bm & ((1ULL << lane) - 1ULL));
    if (tid < 256 && lane == 0) pfxw[wv6] = __popcll(bm);
    __syncthreads();
    {
        int base = 0;
#pragma unroll
        for (int w = 0; w < 4; w++) base += (w < wv6) ? pfxw[w] : 0;
        if (tid < 256 && f) {
            lst[base + rank] = tid;
            inlist[row * MAXDEG + base + rank] = tid;
        }
    }
    if (tid == 0) {
        int tot = pfxw[0] + pfxw[1] + pfxw[2] + pfxw[3];
        lst[tot] = row;                   // GATConv self loop
        inlist[row * MAXDEG + tot] = row;
        dgS = tot + 1;
        deg[row] = tot + 1;
    }
    __syncthreads();
    int dg = dgS;
    for (int p = tid; p < dg * 4; p += 512) {
        int e = p >> 2, hq2 = p & 3;
        int s = lst[e];
        float v = es1[s * 4 + hq2] + ed1[row * 4 + hq2];
        sc[p] = v >= 0.f ? v : 0.2f * v;  // leaky_relu(0.2)
    }
    __syncthreads();
    int hq = tid & 3;
    {
        float lm = -1e30f;
        for (int e = tid >> 2; e < dg; e += 128)
            lm = fmaxf(lm, sc[e * 4 + hq]);
#pragma unroll
        for (int o = 4; o <= 32; o <<= 1) lm = fmaxf(lm, __shfl_xor(lm, o));
        if (lane < 4) sval[wv6 * 4 + hq] = lm;
        __syncthreads();
        float m = sval[hq];
#pragma unroll
        for (int w = 1; w < 8; w++) m = fmaxf(m, sval[w * 4 + hq]);
        float ls = 0.f;
        for (int e = tid >> 2; e < dg; e += 128) {
            float pv = expf(sc[e * 4 + hq] - m);
            sc[e * 4 + hq] = pv;
            ls += pv;
        }
#pragma unroll
        for (int o = 4; o <= 32; o <<= 1) ls += __shfl_xor(ls, o);
        if (lane < 4) sval[32 + wv6 * 4 + hq] = ls;
        __syncthreads();
        float den = sval[32 + hq];
#pragma unroll
        for (int w = 1; w < 8; w++) den += sval[32 + w * 4 + hq];
        for (int e = tid >> 2; e < dg; e += 128)
            sc[e * 4 + hq] = sc[e * 4 + hq] / den;   // alpha
    }
    __syncthreads();
    {
        int col = tid & 255, hh = (tid >> 8) * 2;   // heads {hh, hh+1}
        float acc0 = 0.f, acc1 = 0.f;
        int e = 0;
        for (; e + 8 <= dg; e += 8) {
            float v0[8], v1[8];
#pragma unroll
            for (int u = 0; u < 8; u++) {
                const float* hs = hpre + (size_t)lst[e + u] * M1;
                v0[u] = hs[hh * GCNH + col];
                v1[u] = hs[(hh + 1) * GCNH + col];
            }
#pragma unroll
            for (int u = 0; u < 8; u++) {
                acc0 = fmaf(sc[(e + u) * 4 + hh],     v0[u], acc0);
                acc1 = fmaf(sc[(e + u) * 4 + hh + 1], v1[u], acc1);
            }
        }
        for (; e < dg; e++) {
            const float* hs = hpre + (size_t)lst[e] * M1;
            acc0 = fmaf(sc[e * 4 + hh],     hs[hh * GCNH + col],       acc0);
            acc1 = fmaf(sc[e * 4 + hh + 1], hs[(hh + 1) * GCNH + col], acc1);
        }
        int c0 = hh * GCNH + col, c1 = (hh + 1) * GCNH + col;
        sh[c0] = fmaxf(acc0 + b1[c0], 0.f);
        sh[c1] = fmaxf(acc1 + b1[c1], 0.f);
    }
    __syncthreads();
    if (tid < 504) {                      // 24-way split of 1024 -> 21
        int o = tid % OUTC, pq = tid / OUTC;
        float a2 = 0.f;
        for (int d = pq; d < M1; d += 24)
            a2 = fmaf(sh[d], W2[d * OUTC + o], a2);
        part[pq * OUTC + o] = a2;
    }
    __syncthreads();
    if (tid < OUTC) {
        float ssum = 0.f;
        for (int pq = 0; pq < 24; pq++) ssum += part[pq * OUTC + tid];
        h2[row * OUTC + tid] = ssum;
        h2row[tid] = ssum;
    }
    __syncthreads();
    if (tid == 0) {
        float ssum = 0.f, dd = 0.f;
        for (int k = 0; k < OUTC; k++) {
            ssum = fmaf(h2row[k], as2[k], ssum);
            dd = fmaf(h2row[k], ad2[k], dd);
        }
        es2[row] = ssum;
        ed2[row] = dd;
    }
}

// ---------------------------------------------------------------------------
// Stage D: GAT-2 softmax-aggregate -> logits + argmax. grid 256 x 512.
__global__ __launch_bounds__(512) void k_stD(
        const int* __restrict__ deg, const int* __restrict__ inlist,
        const float* __restrict__ es2, const float* __restrict__ ed2,
        const float* __restrict__ h2, const float* __restrict__ b2,
        float* __restrict__ out) {
    __shared__ float sval[512];
    __shared__ int lst[MAXDEG];
    __shared__ float scD[MAXDEG];
    __shared__ float part[24 * OUTC];
    __shared__ float lv[OUTC];
    int row = blockIdx.x, tid = threadIdx.x;
    int lane = tid & 63, wv6 = tid >> 6;
    int dgT = deg[row];
    float edt = ed2[row];
    for (int p = tid; p < dgT; p += 512) {
        int s = inlist[row * MAXDEG + p];
        lst[p] = s;
        float v = es2[s] + edt;
        scD[p] = v >= 0.f ? v : 0.2f * v;
    }
    __syncthreads();
    {
        float lm = -1e30f;
        for (int p = tid; p < dgT; p += 512) lm = fmaxf(lm, scD[p]);
#pragma unroll
        for (int o = 1; o <= 32; o <<= 1) lm = fmaxf(lm, __shfl_xor(lm, o));
        if (lane == 0) sval[wv6] = lm;
        __syncthreads();
        float m = sval[0];
#pragma unroll
        for (int w = 1; w < 8; w++) m = fmaxf(m, sval[w]);
        float ls = 0.f;
        for (int p = tid; p < dgT; p += 512) {
            float pv = expf(scD[p] - m);
            scD[p] = pv;
            ls += pv;
        }
#pragma unroll
        for (int o = 1; o <= 32; o <<= 1) ls += __shfl_xor(ls, o);
        if (lane == 0) sval[8 + wv6] = ls;
        __syncthreads();
        float den = sval[8];
#pragma unroll
        for (int w = 1; w < 8; w++) den += sval[8 + w];
        __syncthreads();
        if (tid < 504) {                  // (edge-group, out-channel) map
            int o = tid % OUTC, eg = tid / OUTC;
            float acc = 0.f;
            for (int e = eg; e < dgT; e += 24) {
                int s = lst[e];
                acc = fmaf(scD[e], h2[(size_t)s * OUTC + o], acc);
            }
            part[eg * OUTC + o] = acc;
        }
        __syncthreads();
        if (tid < OUTC) {
            float ssum = 0.f;
            for (int eg = 0; eg < 24; eg++) ssum += part[eg * OUTC + tid];
            float v = ssum / den + b2[tid];
            out[row * OUTC + tid] = v;
            lv[tid] = v;
        }
    }
    __syncthreads();
    if (tid == 0) {
        int best = 0;
        float bv = lv[0];
        for (int o = 1; o < OUTC; o++)
            if (lv[o] > bv) { bv = lv[o]; best = o; }  // first max wins
        out[NN * OUTC + row] = (float)best;
    }
}

// ---------------------------------------------------------------------------
extern "C" void kernel_launch(void* const* d_in, const int* in_sizes, int n_in,
                              void* d_out, int out_size, void* d_ws,
                              size_t ws_size, hipStream_t stream) {
    const float* feat  = (const float*)d_in[0];
    const float* boxes = (const float*)d_in[1];
    const float* Wfc1  = (const float*)d_in[2];
    const float* bfc1  = (const float*)d_in[3];
    const float* Wfc2  = (const float*)d_in[4];
    const float* bfc2  = (const float*)d_in[5];   (void)bfc2;
    const float* W1    = (const float*)d_in[6];
    const float* as1   = (const float*)d_in[7];
    const float* ad1   = (const float*)d_in[8];
    const float* b1    = (const float*)d_in[9];
    const float* W2    = (const float*)d_in[10];
    const float* as2   = (const float*)d_in[11];
    const float* ad2   = (const float*)d_in[12];
    const float* b2    = (const float*)d_in[13];
    const int*   imh   = (const int*)d_in[14];
    const int*   imw   = (const int*)d_in[15];

    float* ws = (float*)d_ws;
    float* A     = ws;  ws += NN * HIDR;
    float* BT4   = ws;  ws += NN * HIDR;
    float* hpre  = ws;  ws += NN * M1;
    float* es1   = ws;  ws += NN * 4;
    float* ed1   = ws;  ws += NN * 4;
    float* h2    = ws;  ws += NN * OUTC;
    float* es2   = ws;  ws += NN;
    float* ed2   = ws;  ws += NN;
    int* idxTop  = (int*)ws;
    int* deg     = idxTop + NN * 3;
    int* inlist  = deg + NN;

    float* out = (float*)d_out;

    k_gemm<<<(NN / GBM) * (FCOLS / GBN), 256, 0, stream>>>(
        feat, Wfc1, W1, boxes, imh, imw, bfc1, A, BT4, hpre);
    k_stB<<<NN, 512, 0, stream>>>(A, boxes, Wfc1, Wfc2, BT4, hpre,
                                  as1, ad1, idxTop, es1, ed1);
    k_stC<<<NN, 512, 0, stream>>>(idxTop, es1, ed1, hpre, b1, W2, as2, ad2,
                                  deg, inlist, h2, es2, ed2);
    k_stD<<<NN, 512, 0, stream>>>(deg, inlist, es2, ed2, h2, b2, out);
}